// Round 14
// baseline (397.711 us; speedup 1.0000x reference)
//
#include <hip/hip_runtime.h>

#define LRELU(x) ((x) > 0.f ? (x) : 0.2f * (x))

typedef __attribute__((ext_vector_type(8))) short bf16x8;
typedef __attribute__((ext_vector_type(4))) float f32x4;

__device__ __forceinline__ unsigned short f2bf(float f) {
  unsigned int u = __float_as_uint(f);
  unsigned int r = (u + 0x7fffu + ((u >> 16) & 1u)) >> 16;  // RNE
  return (unsigned short)r;
}
__device__ __forceinline__ float bf2f(unsigned short u) {
  return __uint_as_float(((unsigned int)u) << 16);
}
__device__ __forceinline__ float bflo(unsigned int u) { return __uint_as_float(u << 16); }
__device__ __forceinline__ float bfhi(unsigned int u) { return __uint_as_float(u & 0xffff0000u); }

__device__ __forceinline__ void lgkm0() { asm volatile("s_waitcnt lgkmcnt(0)" ::: "memory"); }

template <int NL>
__device__ __forceinline__ void wait_vmN() {
  if constexpr (NL == 2)      asm volatile("s_waitcnt vmcnt(2)" ::: "memory");
  else if constexpr (NL == 3) asm volatile("s_waitcnt vmcnt(3)" ::: "memory");
  else if constexpr (NL == 4) asm volatile("s_waitcnt vmcnt(4)" ::: "memory");
  else if constexpr (NL == 5) asm volatile("s_waitcnt vmcnt(5)" ::: "memory");
  else if constexpr (NL == 6) asm volatile("s_waitcnt vmcnt(6)" ::: "memory");
  else                        asm volatile("s_waitcnt vmcnt(0)" ::: "memory");
}
__device__ __forceinline__ void wait_vm0() { asm volatile("s_waitcnt vmcnt(0)" ::: "memory"); }

#define GLOAD_LDS16(g, l)                                                  \
  __builtin_amdgcn_global_load_lds(                                        \
      (const __attribute__((address_space(1))) void*)(g),                  \
      (__attribute__((address_space(3))) void*)(l), 16, 0, 0)

// ---- per-wave edge dtype detection ----
__device__ __forceinline__ int wave_detect64(const void* ei) {
  const int* w = (const int*)ei;
  int l = threadIdx.x & 63;
  int v = w[2 * l + 1] | w[2 * l + 129];
  return __ballot(v != 0) == 0ull;  // 1 => int64 layout
}
__device__ __forceinline__ int edge_at(const void* ei, long long idx, int is64) {
  if (is64) return (int)((const long long*)ei)[idx];
  return ((const int*)ei)[idx];
}

// ---- fused prep: tobf16(x) | wprep(W1) | wprep(W2) | hist ----
__global__ __launch_bounds__(256) void prep_all(
    const float* __restrict__ x, unsigned short* __restrict__ xh, int n4,
    const float* __restrict__ W1, unsigned short* __restrict__ W1th,
    unsigned short* __restrict__ W1tl,
    const float* __restrict__ W2, unsigned short* __restrict__ W2th,
    unsigned short* __restrict__ W2tl,
    const void* __restrict__ ei, int* __restrict__ counts, int E, int N,
    int nbX, int nbW1, int nbW2) {
  int b = blockIdx.x;
  int tid = threadIdx.x;
  if (b < nbX) {
    int i = b * 256 + tid;
    if (i < n4) {
      float4 v = ((const float4*)x)[i];
      ushort4 h;
      h.x = f2bf(v.x); h.y = f2bf(v.y); h.z = f2bf(v.z); h.w = f2bf(v.w);
      ((ushort4*)xh)[i] = h;
    }
    return;
  }
  b -= nbX;
  if (b < nbW1) {
    int idx = b * 256 + tid;
    const int K = 128, Nc = 256;
    if (idx < K * Nc) {
      int n = idx / K, k = idx - n * K;
      float v = W1[(size_t)k * Nc + n];
      unsigned short h = f2bf(v);
      W1th[idx] = h;
      W1tl[idx] = f2bf(v - bf2f(h));
    }
    return;
  }
  b -= nbW1;
  if (b < nbW2) {
    int idx = b * 256 + tid;
    const int K = 256, Nc = 64;
    if (idx < K * Nc) {
      int n = idx / K, k = idx - n * K;
      float v = W2[(size_t)k * Nc + n];
      unsigned short h = f2bf(v);
      W2th[idx] = h;
      W2tl[idx] = f2bf(v - bf2f(h));
    }
    return;
  }
  b -= nbW2;
  int is64 = wave_detect64(ei);
  int i = b * 256 + tid;
  int tot = E + N;
  if (i >= tot) return;
  int d = (i < E) ? edge_at(ei, (long long)E + i, is64) : (i - E);
  atomicAdd(&counts[d], 1);
}

// ---- CSR scan (pass 1: per-512-block inclusive) ----
__global__ __launch_bounds__(512) void scan1_kernel(const int* __restrict__ counts,
                                                    int* __restrict__ partial,
                                                    int* __restrict__ blocksums, int N) {
  __shared__ int sm[1024];
  int t = threadIdx.x;
  int i = blockIdx.x * 512 + t;
  int v = (i < N) ? counts[i] : 0;
  int* cur = sm; int* nxt = sm + 512;
  cur[t] = v;
  __syncthreads();
  for (int off = 1; off < 512; off <<= 1) {
    int x = cur[t];
    if (t >= off) x += cur[t - off];
    nxt[t] = x;
    __syncthreads();
    int* tmp = cur; cur = nxt; nxt = tmp;
  }
  if (i < N) partial[i] = cur[t];
  if (t == 511) blocksums[blockIdx.x] = cur[511];
}

// ---- fused scan2+scan3 ----
__global__ __launch_bounds__(256) void scan23_kernel(const int* __restrict__ partial,
                                                     const int* __restrict__ bs,
                                                     int* __restrict__ row_ptr,
                                                     int* __restrict__ cursor, int N, int SB) {
  __shared__ int bsp[128];
  int tid = threadIdx.x;
  if (tid < 64) {
    int l = tid;
    int a0 = (l < SB) ? bs[l] : 0;
    int a1 = (l + 64 < SB) ? bs[l + 64] : 0;
    int s0 = a0, s1 = a1;
#pragma unroll
    for (int o = 1; o < 64; o <<= 1) {
      int t0 = __shfl_up(s0, o);
      int t1 = __shfl_up(s1, o);
      if (l >= o) { s0 += t0; s1 += t1; }
    }
    int tot0 = __shfl(s0, 63);
    bsp[l] = s0 - a0;
    bsp[l + 64] = tot0 + s1 - a1;
  }
  __syncthreads();
  int i = blockIdx.x * 256 + tid;
  if (i == 0) { row_ptr[0] = 0; cursor[0] = 0; }
  if (i < N) {
    int v = partial[i] + bsp[i >> 9];
    row_ptr[i + 1] = v;
    if (i + 1 < N) cursor[i + 1] = v;
  }
}

__global__ void scatter_kernel(const void* __restrict__ ei,
                               int* __restrict__ cursor, int* __restrict__ srcs, int E, int N) {
  int is64 = wave_detect64(ei);
  int i = blockIdx.x * blockDim.x + threadIdx.x;
  int tot = E + N;
  if (i >= tot) return;
  int s, d;
  if (i < E) {
    s = edge_at(ei, i, is64);
    d = edge_at(ei, (long long)E + i, is64);
  } else {
    s = i - E; d = s;
  }
  int pos = atomicAdd(&cursor[d], 1);
  srcs[pos] = s;
}

// ---- MFMA GEMM, fused segments: per k-step stage {A, B0, B1}, acc += A@B0 + A@B1 ----
template <int BROWS, int BCOLS, int WM, int WN, int H>
__global__ __launch_bounds__(256) void gemm_mfma(
    const unsigned short* __restrict__ A0, const unsigned short* __restrict__ B0,
    const unsigned short* __restrict__ B1, int M, int Ka,
    unsigned short* __restrict__ Cb, int ldc, const float* __restrict__ asrc,
    const float* __restrict__ adst, float* __restrict__ as, float* __restrict__ ad) {
  constexpr int WROWS = BROWS / WM;
  constexpr int WCOLS = BCOLS / WN;
  constexpr int MR = WROWS / 16;
  constexpr int NR = WCOLS / 16;
  constexpr int CH_A = BROWS / 64;
  constexpr int CH_B = BCOLS / 64;
  constexpr int NLOADS = CH_A + 2 * CH_B;
  __shared__ __align__(16) unsigned short Asm[2][4][BROWS][8];
  __shared__ __align__(16) unsigned short Bsm[2][2][4][BCOLS][8];
  int tid = threadIdx.x;
  int w = tid >> 6, l = tid & 63;
  int wm = w / WN, wn = w % WN;
  int l16 = l & 15, lg = l >> 4;
  int rowbase = blockIdx.y * BROWS;
  int colbase = blockIdx.x * BCOLS;
  int wrow = wm * WROWS, wcol = wn * WCOLS;
  const int KS = Ka / 32;

  auto stage = [&](int buf, int s) {
    int kk = s * 32;
#pragma unroll
    for (int q = 0; q < CH_A; ++q) {
      int i = q * 256 + tid;
      int p = i / BROWS, r = i % BROWS;
      int gr = rowbase + r;
      if (gr >= M) gr = M - 1;
      const unsigned short* src = A0 + (size_t)gr * Ka + kk + p * 8;
      unsigned short* dst = &Asm[buf][0][0][0] + ((size_t)q * 256 + (tid & ~63)) * 8;
      GLOAD_LDS16(src, dst);
    }
#pragma unroll
    for (int seg = 0; seg < 2; ++seg) {
      const unsigned short* Bp = seg ? B1 : B0;
#pragma unroll
      for (int q = 0; q < CH_B; ++q) {
        int i = q * 256 + tid;
        int p = i / BCOLS, r = i % BCOLS;
        const unsigned short* src = Bp + (size_t)(colbase + r) * Ka + kk + p * 8;
        unsigned short* dst = &Bsm[buf][seg][0][0][0] + ((size_t)q * 256 + (tid & ~63)) * 8;
        GLOAD_LDS16(src, dst);
      }
    }
  };

  f32x4 acc[MR][NR] = {};
  stage(0, 0);
  int buf = 0;
  for (int s = 0; s < KS; ++s) {
    if (s + 1 < KS) { stage(buf ^ 1, s + 1); wait_vmN<NLOADS>(); }
    else            { wait_vm0(); }
    __builtin_amdgcn_s_barrier();
    bf16x8 af[MR], bf0[NR], bf1[NR];
#pragma unroll
    for (int m = 0; m < MR; ++m) af[m] = *(const bf16x8*)&Asm[buf][lg][wrow + m * 16 + l16][0];
#pragma unroll
    for (int n = 0; n < NR; ++n) {
      bf0[n] = *(const bf16x8*)&Bsm[buf][0][lg][wcol + n * 16 + l16][0];
      bf1[n] = *(const bf16x8*)&Bsm[buf][1][lg][wcol + n * 16 + l16][0];
    }
#pragma unroll
    for (int m = 0; m < MR; ++m)
#pragma unroll
      for (int n = 0; n < NR; ++n)
        acc[m][n] = __builtin_amdgcn_mfma_f32_16x16x32_bf16(af[m], bf0[n], acc[m][n], 0, 0, 0);
#pragma unroll
    for (int m = 0; m < MR; ++m)
#pragma unroll
      for (int n = 0; n < NR; ++n)
        acc[m][n] = __builtin_amdgcn_mfma_f32_16x16x32_bf16(af[m], bf1[n], acc[m][n], 0, 0, 0);
    __builtin_amdgcn_s_barrier();
    buf ^= 1;
  }
#pragma unroll
  for (int m = 0; m < MR; ++m) {
    int r = rowbase + wrow + m * 16 + lg * 4;
#pragma unroll
    for (int n = 0; n < NR; ++n) {
      int c = colbase + wcol + n * 16 + l16;
#pragma unroll
      for (int j = 0; j < 4; ++j) {
        if (r + j < M) Cb[(size_t)(r + j) * ldc + c] = f2bf(acc[m][n][j]);
      }
    }
  }
  float asv[NR], adv_[NR];
#pragma unroll
  for (int n = 0; n < NR; ++n) {
    int c = colbase + wcol + n * 16 + l16;
    asv[n] = asrc[c];
    adv_[n] = adst[c];
  }
  int head = (H == 1) ? 0 : ((colbase + wcol) >> 6);
#pragma unroll
  for (int m = 0; m < MR; ++m) {
#pragma unroll
    for (int j = 0; j < 4; ++j) {
      float ps = 0.f, pd = 0.f;
#pragma unroll
      for (int n = 0; n < NR; ++n) {
        ps = fmaf(acc[m][n][j], asv[n], ps);
        pd = fmaf(acc[m][n][j], adv_[n], pd);
      }
#pragma unroll
      for (int o = 1; o < 16; o <<= 1) { ps += __shfl_xor(ps, o); pd += __shfl_xor(pd, o); }
      int r = rowbase + wrow + m * 16 + lg * 4 + j;
      if (l16 == 0 && r < M) {
        as[(size_t)r * H + head] = ps;
        ad[(size_t)r * H + head] = pd;
      }
    }
  }
}

// ---- alpha_edge: wave per node; no-max softmax; writes normalized per-edge alpha ----
__global__ __launch_bounds__(256) void alpha_edge(const float* __restrict__ as,
                                                  const float* __restrict__ ad,
                                                  const int* __restrict__ row_ptr,
                                                  const int* __restrict__ srcs,
                                                  float* __restrict__ ae, int N) {
  __shared__ float els[4][128][4];
  int tid = threadIdx.x;
  int w = tid >> 6, l = tid & 63;
  int gw = (blockIdx.x << 2) + w;
  if (gw >= N) gw = N - 1;
  int beg = row_ptr[gw], end = row_ptr[gw + 1];
  float4 adv = *(const float4*)(ad + (size_t)gw * 4);
  float s0 = 0.f, s1 = 0.f, s2 = 0.f, s3 = 0.f;
  for (int j = beg + l; j < end; j += 64) {
    int sn = srcs[j];
    float4 a = *(const float4*)(as + (size_t)sn * 4);
    float x0 = __expf(LRELU(a.x + adv.x));
    float x1 = __expf(LRELU(a.y + adv.y));
    float x2 = __expf(LRELU(a.z + adv.z));
    float x3 = __expf(LRELU(a.w + adv.w));
    int slot = j - beg;
    if (slot < 128) {
      els[w][slot][0] = x0; els[w][slot][1] = x1;
      els[w][slot][2] = x2; els[w][slot][3] = x3;
    }
    s0 += x0; s1 += x1; s2 += x2; s3 += x3;
  }
#pragma unroll
  for (int o = 32; o; o >>= 1) {
    s0 += __shfl_xor(s0, o); s1 += __shfl_xor(s1, o);
    s2 += __shfl_xor(s2, o); s3 += __shfl_xor(s3, o);
  }
  float i0 = 1.f / (s0 + 1e-16f), i1 = 1.f / (s1 + 1e-16f);
  float i2 = 1.f / (s2 + 1e-16f), i3 = 1.f / (s3 + 1e-16f);
  lgkm0();
  for (int j = beg + l; j < end; j += 64) {
    int slot = j - beg;
    float x0, x1, x2, x3;
    if (slot < 128) {
      x0 = els[w][slot][0]; x1 = els[w][slot][1];
      x2 = els[w][slot][2]; x3 = els[w][slot][3];
    } else {
      int sn = srcs[j];
      float4 a = *(const float4*)(as + (size_t)sn * 4);
      x0 = __expf(LRELU(a.x + adv.x));
      x1 = __expf(LRELU(a.y + adv.y));
      x2 = __expf(LRELU(a.z + adv.z));
      x3 = __expf(LRELU(a.w + adv.w));
    }
    float4 o = make_float4(x0 * i0, x1 * i1, x2 * i2, x3 * i3);
    *(float4*)(ae + (size_t)j * 4) = o;
  }
}

// ---- agg4s: XCD-sliced gather. grid (8 slices, N/4); slice owns 32 channels. ----
// Wave per (node, slice). lane=(g in [0,4), p in [0,16)); p owns 2 channels.
__global__ __launch_bounds__(256) void agg4s(const unsigned short* __restrict__ hb,
                                             const float* __restrict__ ae,
                                             const int* __restrict__ row_ptr,
                                             const int* __restrict__ srcs,
                                             const float* __restrict__ bias,
                                             unsigned short* __restrict__ oh, int N) {
  int tid = threadIdx.x;
  int w = tid >> 6, l = tid & 63;
  int gw = (blockIdx.y << 2) + w;
  if (gw >= N) gw = N - 1;
  int s = blockIdx.x;      // slice 0..7 -> XCD via round-robin
  int head = s >> 1;
  int g = l >> 4, p = l & 15;
  int beg = row_ptr[gw], end = row_ptr[gw + 1];
  const unsigned short* hbase = hb + (size_t)s * 32 + p * 2;
  float a0 = 0.f, a1 = 0.f;
  // 2-deep pipeline over 4 edge-groups
  int j = beg + g;
  float xA = 0.f; unsigned int vA = 0;
  if (j < end) {
    int sn = srcs[j];
    xA = ae[(size_t)j * 4 + head];
    vA = *(const unsigned int*)(hbase + (size_t)sn * 256);
  }
  while (j < end) {
    int jn = j + 4;
    float xB = 0.f; unsigned int vB = 0;
    if (jn < end) {
      int sn = srcs[jn];
      xB = ae[(size_t)jn * 4 + head];
      vB = *(const unsigned int*)(hbase + (size_t)sn * 256);
    }
    a0 = fmaf(xA, bflo(vA), a0);
    a1 = fmaf(xA, bfhi(vA), a1);
    j = jn; xA = xB; vA = vB;
  }
  a0 += __shfl_xor(a0, 16); a1 += __shfl_xor(a1, 16);
  a0 += __shfl_xor(a0, 32); a1 += __shfl_xor(a1, 32);
  if (g == 0) {
    int c = s * 32 + p * 2;
    float o0 = fmaxf(a0 + bias[c], 0.f);
    float o1 = fmaxf(a1 + bias[c + 1], 0.f);
    unsigned int pk = ((unsigned int)f2bf(o1) << 16) | (unsigned int)f2bf(o0);
    *(unsigned int*)(oh + (size_t)gw * 256 + c) = pk;
  }
}

// ---- layer-2 aggregation: no-max softmax, exp+src stash, 3-deep pipeline ----
// lane=(g in [0,8), p in [0,8)); p owns 8 channels
__global__ __launch_bounds__(256) void agg1(const unsigned short* __restrict__ hb,
                                            const float* __restrict__ as,
                                            const float* __restrict__ ad,
                                            const int* __restrict__ row_ptr,
                                            const int* __restrict__ srcs,
                                            const float* __restrict__ bias,
                                            float* __restrict__ out, int N) {
  __shared__ float els[4][128];
  __shared__ int   sls[4][128];
  int tid = threadIdx.x;
  int w = tid >> 6, l = tid & 63;
  int gw = (blockIdx.x << 2) + w;
  if (gw >= N) gw = N - 1;
  int g = l >> 3, p = l & 7;
  int beg = row_ptr[gw], end = row_ptr[gw + 1];
  float adn = ad[gw];
  float s = 0.f;
  for (int j = beg + l; j < end; j += 64) {
    int sn = srcs[j];
    float x = __expf(LRELU(as[sn] + adn));
    int slot = j - beg;
    if (slot < 128) { els[w][slot] = x; sls[w][slot] = sn; }
    s += x;
  }
#pragma unroll
  for (int o = 32; o; o >>= 1) s += __shfl_xor(s, o);
  float inv = 1.f / (s + 1e-16f);
  lgkm0();
  float acc[8] = {};
  int jbase = beg + g;
  float xA = 0.f, xB = 0.f;
  uint4 vA = {}, vB = {};
  if (jbase < end) {
    int slot = jbase - beg;
    int sn;
    if (slot < 128) { sn = sls[w][slot]; xA = els[w][slot]; }
    else { sn = srcs[jbase]; xA = __expf(LRELU(as[sn] + adn)); }
    vA = *(const uint4*)(hb + (size_t)sn * 64 + p * 8);
  }
  if (jbase + 8 < end) {
    int slot = jbase + 8 - beg;
    int sn;
    if (slot < 128) { sn = sls[w][slot]; xB = els[w][slot]; }
    else { sn = srcs[jbase + 8]; xB = __expf(LRELU(as[sn] + adn)); }
    vB = *(const uint4*)(hb + (size_t)sn * 64 + p * 8);
  }
  for (int j = jbase; j < end; j += 8) {
    int jp = j + 16;
    float xC = 0.f; uint4 vC = {};
    if (jp < end) {
      int slot = jp - beg;
      int sn;
      if (slot < 128) { sn = sls[w][slot]; xC = els[w][slot]; }
      else { sn = srcs[jp]; xC = __expf(LRELU(as[sn] + adn)); }
      vC = *(const uint4*)(hb + (size_t)sn * 64 + p * 8);
    }
    float al = xA * inv;
    acc[0] = fmaf(al, bflo(vA.x), acc[0]); acc[1] = fmaf(al, bfhi(vA.x), acc[1]);
    acc[2] = fmaf(al, bflo(vA.y), acc[2]); acc[3] = fmaf(al, bfhi(vA.y), acc[3]);
    acc[4] = fmaf(al, bflo(vA.z), acc[4]); acc[5] = fmaf(al, bfhi(vA.z), acc[5]);
    acc[6] = fmaf(al, bflo(vA.w), acc[6]); acc[7] = fmaf(al, bfhi(vA.w), acc[7]);
    xA = xB; vA = vB;
    xB = xC; vB = vC;
  }
#pragma unroll
  for (int i = 0; i < 8; ++i) acc[i] += __shfl_xor(acc[i], 8);
#pragma unroll
  for (int i = 0; i < 8; ++i) acc[i] += __shfl_xor(acc[i], 16);
#pragma unroll
  for (int i = 0; i < 8; ++i) acc[i] += __shfl_xor(acc[i], 32);
  float ov = g == 0 ? acc[0] : g == 1 ? acc[1] : g == 2 ? acc[2] : g == 3 ? acc[3]
           : g == 4 ? acc[4] : g == 5 ? acc[5] : g == 6 ? acc[6] : acc[7];
  int c = p * 8 + g;
  out[(size_t)gw * 64 + c] = ov + bias[c];
}

extern "C" void kernel_launch(void* const* d_in, const int* in_sizes, int n_in,
                              void* d_out, int out_size, void* d_ws, size_t ws_size,
                              hipStream_t stream) {
  const float* x      = (const float*)d_in[0];
  const void*  ei     = d_in[1];
  const float* W1     = (const float*)d_in[2];
  const float* a_src1 = (const float*)d_in[3];
  const float* a_dst1 = (const float*)d_in[4];
  const float* b1     = (const float*)d_in[5];
  const float* W2     = (const float*)d_in[6];
  const float* a_src2 = (const float*)d_in[7];
  const float* a_dst2 = (const float*)d_in[8];
  const float* b2     = (const float*)d_in[9];

  const int Fin = 128;
  const int N   = in_sizes[0] / Fin;  // 50000
  const int E   = in_sizes[1] / 2;    // 800000
  const int HC1 = in_sizes[2] / Fin;  // 256
  const int Etot = E + N;

  char* wp = (char*)d_ws;
  auto alloc = [&](size_t bytes) {
    void* p = (void*)wp;
    wp += (bytes + 255) & ~(size_t)255;
    return p;
  };
  int* counts    = (int*)alloc((size_t)N * 4);
  int* row_ptr   = (int*)alloc((size_t)(N + 1) * 4);
  int* cursor    = (int*)alloc((size_t)N * 4);
  int* partial   = (int*)alloc((size_t)N * 4);
  int* blocksums = (int*)alloc(4096);
  int* srcs      = (int*)alloc((size_t)Etot * 4);
  unsigned short* xh   = (unsigned short*)alloc((size_t)N * Fin * 2);   // 12.8MB
  unsigned short* xpad = (unsigned short*)alloc((size_t)N * Fin * 2);   // o1h tail region
  unsigned short* W1th = (unsigned short*)alloc((size_t)HC1 * Fin * 2);
  unsigned short* W1tl = (unsigned short*)alloc((size_t)HC1 * Fin * 2);
  unsigned short* W2th = (unsigned short*)alloc((size_t)64 * HC1 * 2);
  unsigned short* W2tl = (unsigned short*)alloc((size_t)64 * HC1 * 2);
  unsigned short* h1b  = (unsigned short*)alloc((size_t)N * 256 * 2);   // 25.6MB
  float* as1 = (float*)alloc((size_t)N * 4 * 4);
  float* ad1 = (float*)alloc((size_t)N * 4 * 4);
  float* as2 = (float*)alloc((size_t)N * 4);
  float* ad2 = (float*)alloc((size_t)N * 4);
  float* ae  = (float*)alloc((size_t)Etot * 4 * 4);  // 13.6MB per-edge alphas
  (void)xpad;
  unsigned short* o1h = xh;   // xh dead after gemm1; xh+xpad = 25.6MB contiguous
  unsigned short* h2b = h1b;  // h1b dead after agg4s

  const int SB = (N + 511) / 512;
  const int n4 = N * Fin / 4;
  const int nbX  = (n4 + 255) / 256;
  const int nbW1 = (Fin * HC1 + 255) / 256;
  const int nbW2 = (HC1 * 64 + 255) / 256;
  const int nbH  = (Etot + 255) / 256;

  // ---- fused prep (tobf16 | wprep1 | wprep2 | hist) ----
  hipMemsetAsync(counts, 0, (size_t)N * 4, stream);
  prep_all<<<nbX + nbW1 + nbW2 + nbH, 256, 0, stream>>>(
      x, xh, n4, W1, W1th, W1tl, W2, W2th, W2tl, ei, counts, E, N, nbX, nbW1, nbW2);

  // ---- CSR scan + scatter ----
  scan1_kernel<<<SB, 512, 0, stream>>>(counts, partial, blocksums, N);
  scan23_kernel<<<(N + 255) / 256, 256, 0, stream>>>(partial, blocksums, row_ptr, cursor, N, SB);
  scatter_kernel<<<(Etot + 255) / 256, 256, 0, stream>>>(ei, cursor, srcs, E, N);

  // ---- layer 1: fused-seg MFMA GEMM + per-edge alphas + XCD-sliced gather ----
  gemm_mfma<128, 128, 2, 2, 4><<<dim3(2, (N + 127) / 128), 256, 0, stream>>>(
      xh, W1th, W1tl, N, Fin, h1b, 256, a_src1, a_dst1, as1, ad1);
  alpha_edge<<<(N + 3) / 4, 256, 0, stream>>>(as1, ad1, row_ptr, srcs, ae, N);
  agg4s<<<dim3(8, (N + 3) / 4), 256, 0, stream>>>(h1b, ae, row_ptr, srcs, b1, o1h, N);

  // ---- layer 2: fused-seg MFMA GEMM + aggregation ----
  gemm_mfma<64, 64, 4, 1, 1><<<dim3(1, (N + 63) / 64), 256, 0, stream>>>(
      o1h, W2th, W2tl, N, HC1, h2b, 64, a_src2, a_dst2, as2, ad2);
  agg1<<<(N + 3) / 4, 256, 0, stream>>>(h2b, as2, ad2, row_ptr, srcs, b2, (float*)d_out, N);
}

// Round 15
// 239.661 us; speedup vs baseline: 1.6595x; 1.6595x over previous
//
#include <hip/hip_runtime.h>

#define LRELU(x) ((x) > 0.f ? (x) : 0.2f * (x))

typedef __attribute__((ext_vector_type(8))) short bf16x8;
typedef __attribute__((ext_vector_type(4))) float f32x4;

__device__ __forceinline__ unsigned short f2bf(float f) {
  unsigned int u = __float_as_uint(f);
  unsigned int r = (u + 0x7fffu + ((u >> 16) & 1u)) >> 16;  // RNE
  return (unsigned short)r;
}
__device__ __forceinline__ float bf2f(unsigned short u) {
  return __uint_as_float(((unsigned int)u) << 16);
}
__device__ __forceinline__ float bflo(unsigned int u) { return __uint_as_float(u << 16); }
__device__ __forceinline__ float bfhi(unsigned int u) { return __uint_as_float(u & 0xffff0000u); }

__device__ __forceinline__ void lgkm0() { asm volatile("s_waitcnt lgkmcnt(0)" ::: "memory"); }

template <int NL>
__device__ __forceinline__ void wait_vmN() {
  if constexpr (NL == 2)      asm volatile("s_waitcnt vmcnt(2)" ::: "memory");
  else if constexpr (NL == 3) asm volatile("s_waitcnt vmcnt(3)" ::: "memory");
  else if constexpr (NL == 4) asm volatile("s_waitcnt vmcnt(4)" ::: "memory");
  else if constexpr (NL == 5) asm volatile("s_waitcnt vmcnt(5)" ::: "memory");
  else if constexpr (NL == 6) asm volatile("s_waitcnt vmcnt(6)" ::: "memory");
  else                        asm volatile("s_waitcnt vmcnt(0)" ::: "memory");
}
__device__ __forceinline__ void wait_vm0() { asm volatile("s_waitcnt vmcnt(0)" ::: "memory"); }

#define GLOAD_LDS16(g, l)                                                  \
  __builtin_amdgcn_global_load_lds(                                        \
      (const __attribute__((address_space(1))) void*)(g),                  \
      (__attribute__((address_space(3))) void*)(l), 16, 0, 0)

// ---- per-wave edge dtype detection ----
__device__ __forceinline__ int wave_detect64(const void* ei) {
  const int* w = (const int*)ei;
  int l = threadIdx.x & 63;
  int v = w[2 * l + 1] | w[2 * l + 129];
  return __ballot(v != 0) == 0ull;  // 1 => int64 layout
}
__device__ __forceinline__ int edge_at(const void* ei, long long idx, int is64) {
  if (is64) return (int)((const long long*)ei)[idx];
  return ((const int*)ei)[idx];
}

// ---- fused prep: tobf16(x) | wprep(W1) | wprep(W2) | hist ----
__global__ __launch_bounds__(256) void prep_all(
    const float* __restrict__ x, unsigned short* __restrict__ xh, int n4,
    const float* __restrict__ W1, unsigned short* __restrict__ W1th,
    unsigned short* __restrict__ W1tl,
    const float* __restrict__ W2, unsigned short* __restrict__ W2th,
    unsigned short* __restrict__ W2tl,
    const void* __restrict__ ei, int* __restrict__ counts, int E, int N,
    int nbX, int nbW1, int nbW2) {
  int b = blockIdx.x;
  int tid = threadIdx.x;
  if (b < nbX) {
    int i = b * 256 + tid;
    if (i < n4) {
      float4 v = ((const float4*)x)[i];
      ushort4 h;
      h.x = f2bf(v.x); h.y = f2bf(v.y); h.z = f2bf(v.z); h.w = f2bf(v.w);
      ((ushort4*)xh)[i] = h;
    }
    return;
  }
  b -= nbX;
  if (b < nbW1) {
    int idx = b * 256 + tid;
    const int K = 128, Nc = 256;
    if (idx < K * Nc) {
      int n = idx / K, k = idx - n * K;
      float v = W1[(size_t)k * Nc + n];
      unsigned short h = f2bf(v);
      W1th[idx] = h;
      W1tl[idx] = f2bf(v - bf2f(h));
    }
    return;
  }
  b -= nbW1;
  if (b < nbW2) {
    int idx = b * 256 + tid;
    const int K = 256, Nc = 64;
    if (idx < K * Nc) {
      int n = idx / K, k = idx - n * K;
      float v = W2[(size_t)k * Nc + n];
      unsigned short h = f2bf(v);
      W2th[idx] = h;
      W2tl[idx] = f2bf(v - bf2f(h));
    }
    return;
  }
  b -= nbW2;
  int is64 = wave_detect64(ei);
  int i = b * 256 + tid;
  int tot = E + N;
  if (i >= tot) return;
  int d = (i < E) ? edge_at(ei, (long long)E + i, is64) : (i - E);
  atomicAdd(&counts[d], 1);
}

// ---- CSR scan (pass 1: per-512-block inclusive) ----
__global__ __launch_bounds__(512) void scan1_kernel(const int* __restrict__ counts,
                                                    int* __restrict__ partial,
                                                    int* __restrict__ blocksums, int N) {
  __shared__ int sm[1024];
  int t = threadIdx.x;
  int i = blockIdx.x * 512 + t;
  int v = (i < N) ? counts[i] : 0;
  int* cur = sm; int* nxt = sm + 512;
  cur[t] = v;
  __syncthreads();
  for (int off = 1; off < 512; off <<= 1) {
    int x = cur[t];
    if (t >= off) x += cur[t - off];
    nxt[t] = x;
    __syncthreads();
    int* tmp = cur; cur = nxt; nxt = tmp;
  }
  if (i < N) partial[i] = cur[t];
  if (t == 511) blocksums[blockIdx.x] = cur[511];
}

// ---- fused scan2+scan3: redundant wave-scan of blocksums, then elementwise ----
__global__ __launch_bounds__(256) void scan23_kernel(const int* __restrict__ partial,
                                                     const int* __restrict__ bs,
                                                     int* __restrict__ row_ptr,
                                                     int* __restrict__ cursor, int N, int SB) {
  __shared__ int bsp[128];
  int tid = threadIdx.x;
  if (tid < 64) {
    int l = tid;
    int a0 = (l < SB) ? bs[l] : 0;
    int a1 = (l + 64 < SB) ? bs[l + 64] : 0;
    int s0 = a0, s1 = a1;
#pragma unroll
    for (int o = 1; o < 64; o <<= 1) {
      int t0 = __shfl_up(s0, o);
      int t1 = __shfl_up(s1, o);
      if (l >= o) { s0 += t0; s1 += t1; }
    }
    int tot0 = __shfl(s0, 63);
    bsp[l] = s0 - a0;          // exclusive prefix
    bsp[l + 64] = tot0 + s1 - a1;
  }
  __syncthreads();
  int i = blockIdx.x * 256 + tid;
  if (i == 0) { row_ptr[0] = 0; cursor[0] = 0; }
  if (i < N) {
    int v = partial[i] + bsp[i >> 9];
    row_ptr[i + 1] = v;
    if (i + 1 < N) cursor[i + 1] = v;
  }
}

__global__ void scatter_kernel(const void* __restrict__ ei,
                               int* __restrict__ cursor, int* __restrict__ srcs, int E, int N) {
  int is64 = wave_detect64(ei);
  int i = blockIdx.x * blockDim.x + threadIdx.x;
  int tot = E + N;
  if (i >= tot) return;
  int s, d;
  if (i < E) {
    s = edge_at(ei, i, is64);
    d = edge_at(ei, (long long)E + i, is64);
  } else {
    s = i - E; d = s;
  }
  int pos = atomicAdd(&cursor[d], 1);
  srcs[pos] = s;
}

// ---- MFMA GEMM, fused segments: per k-step stage {A, B0, B1}, acc += A@B0 + A@B1 ----
template <int BROWS, int BCOLS, int WM, int WN, int H>
__global__ __launch_bounds__(256) void gemm_mfma(
    const unsigned short* __restrict__ A0, const unsigned short* __restrict__ B0,
    const unsigned short* __restrict__ B1, int M, int Ka,
    unsigned short* __restrict__ Cb, int ldc, const float* __restrict__ asrc,
    const float* __restrict__ adst, float* __restrict__ as, float* __restrict__ ad) {
  constexpr int WROWS = BROWS / WM;
  constexpr int WCOLS = BCOLS / WN;
  constexpr int MR = WROWS / 16;
  constexpr int NR = WCOLS / 16;
  constexpr int CH_A = BROWS / 64;
  constexpr int CH_B = BCOLS / 64;
  constexpr int NLOADS = CH_A + 2 * CH_B;
  __shared__ __align__(16) unsigned short Asm[2][4][BROWS][8];
  __shared__ __align__(16) unsigned short Bsm[2][2][4][BCOLS][8];
  int tid = threadIdx.x;
  int w = tid >> 6, l = tid & 63;
  int wm = w / WN, wn = w % WN;
  int l16 = l & 15, lg = l >> 4;
  int rowbase = blockIdx.y * BROWS;
  int colbase = blockIdx.x * BCOLS;
  int wrow = wm * WROWS, wcol = wn * WCOLS;
  const int KS = Ka / 32;

  auto stage = [&](int buf, int s) {
    int kk = s * 32;
#pragma unroll
    for (int q = 0; q < CH_A; ++q) {
      int i = q * 256 + tid;
      int p = i / BROWS, r = i % BROWS;
      int gr = rowbase + r;
      if (gr >= M) gr = M - 1;
      const unsigned short* src = A0 + (size_t)gr * Ka + kk + p * 8;
      unsigned short* dst = &Asm[buf][0][0][0] + ((size_t)q * 256 + (tid & ~63)) * 8;
      GLOAD_LDS16(src, dst);
    }
#pragma unroll
    for (int seg = 0; seg < 2; ++seg) {
      const unsigned short* Bp = seg ? B1 : B0;
#pragma unroll
      for (int q = 0; q < CH_B; ++q) {
        int i = q * 256 + tid;
        int p = i / BCOLS, r = i % BCOLS;
        const unsigned short* src = Bp + (size_t)(colbase + r) * Ka + kk + p * 8;
        unsigned short* dst = &Bsm[buf][seg][0][0][0] + ((size_t)q * 256 + (tid & ~63)) * 8;
        GLOAD_LDS16(src, dst);
      }
    }
  };

  f32x4 acc[MR][NR] = {};
  stage(0, 0);
  int buf = 0;
  for (int s = 0; s < KS; ++s) {
    if (s + 1 < KS) { stage(buf ^ 1, s + 1); wait_vmN<NLOADS>(); }
    else            { wait_vm0(); }
    __builtin_amdgcn_s_barrier();
    bf16x8 af[MR], bf0[NR], bf1[NR];
#pragma unroll
    for (int m = 0; m < MR; ++m) af[m] = *(const bf16x8*)&Asm[buf][lg][wrow + m * 16 + l16][0];
#pragma unroll
    for (int n = 0; n < NR; ++n) {
      bf0[n] = *(const bf16x8*)&Bsm[buf][0][lg][wcol + n * 16 + l16][0];
      bf1[n] = *(const bf16x8*)&Bsm[buf][1][lg][wcol + n * 16 + l16][0];
    }
#pragma unroll
    for (int m = 0; m < MR; ++m)
#pragma unroll
      for (int n = 0; n < NR; ++n)
        acc[m][n] = __builtin_amdgcn_mfma_f32_16x16x32_bf16(af[m], bf0[n], acc[m][n], 0, 0, 0);
#pragma unroll
    for (int m = 0; m < MR; ++m)
#pragma unroll
      for (int n = 0; n < NR; ++n)
        acc[m][n] = __builtin_amdgcn_mfma_f32_16x16x32_bf16(af[m], bf1[n], acc[m][n], 0, 0, 0);
    __builtin_amdgcn_s_barrier();
    buf ^= 1;
  }
#pragma unroll
  for (int m = 0; m < MR; ++m) {
    int r = rowbase + wrow + m * 16 + lg * 4;
#pragma unroll
    for (int n = 0; n < NR; ++n) {
      int c = colbase + wcol + n * 16 + l16;
#pragma unroll
      for (int j = 0; j < 4; ++j) {
        if (r + j < M) Cb[(size_t)(r + j) * ldc + c] = f2bf(acc[m][n][j]);
      }
    }
  }
  float asv[NR], adv_[NR];
#pragma unroll
  for (int n = 0; n < NR; ++n) {
    int c = colbase + wcol + n * 16 + l16;
    asv[n] = asrc[c];
    adv_[n] = adst[c];
  }
  int head = (H == 1) ? 0 : ((colbase + wcol) >> 6);
#pragma unroll
  for (int m = 0; m < MR; ++m) {
#pragma unroll
    for (int j = 0; j < 4; ++j) {
      float ps = 0.f, pd = 0.f;
#pragma unroll
      for (int n = 0; n < NR; ++n) {
        ps = fmaf(acc[m][n][j], asv[n], ps);
        pd = fmaf(acc[m][n][j], adv_[n], pd);
      }
#pragma unroll
      for (int o = 1; o < 16; o <<= 1) { ps += __shfl_xor(ps, o); pd += __shfl_xor(pd, o); }
      int r = rowbase + wrow + m * 16 + lg * 4 + j;
      if (l16 == 0 && r < M) {
        as[(size_t)r * H + head] = ps;
        ad[(size_t)r * H + head] = pd;
      }
    }
  }
}

// ---- layer-1 aggregation: no-max softmax, exp+src stashed in LDS, 2-deep pipe ----
__global__ __launch_bounds__(256) void agg4(const unsigned short* __restrict__ hb,
                                            const float* __restrict__ as,
                                            const float* __restrict__ ad,
                                            const int* __restrict__ row_ptr,
                                            const int* __restrict__ srcs,
                                            const float* __restrict__ bias,
                                            unsigned short* __restrict__ oh, int N) {
  __shared__ float els[4][128][4];  // exp(e) per slot per head
  __shared__ int   sls[4][128];     // src index per slot
  int tid = threadIdx.x;
  int w = tid >> 6, l = tid & 63;
  int gw = (blockIdx.x << 2) + w;
  if (gw >= N) gw = N - 1;
  int g = l >> 4, p = l & 15;
  int beg = row_ptr[gw], end = row_ptr[gw + 1];
  float4 adv = *(const float4*)(ad + (size_t)gw * 4);
  // Phase A: one strided pass: exp(e) -> stash + sum; src index -> stash
  float s0 = 0.f, s1 = 0.f, s2 = 0.f, s3 = 0.f;
  for (int j = beg + l; j < end; j += 64) {
    int sn = srcs[j];
    float4 a = *(const float4*)(as + (size_t)sn * 4);
    float x0 = __expf(LRELU(a.x + adv.x));
    float x1 = __expf(LRELU(a.y + adv.y));
    float x2 = __expf(LRELU(a.z + adv.z));
    float x3 = __expf(LRELU(a.w + adv.w));
    int slot = j - beg;
    if (slot < 128) {
      els[w][slot][0] = x0; els[w][slot][1] = x1;
      els[w][slot][2] = x2; els[w][slot][3] = x3;
      sls[w][slot] = sn;
    }
    s0 += x0; s1 += x1; s2 += x2; s3 += x3;
  }
#pragma unroll
  for (int o = 32; o; o >>= 1) {
    s0 += __shfl_xor(s0, o); s1 += __shfl_xor(s1, o);
    s2 += __shfl_xor(s2, o); s3 += __shfl_xor(s3, o);
  }
  float i0 = 1.f / (s0 + 1e-16f), i1 = 1.f / (s1 + 1e-16f);
  float i2 = 1.f / (s2 + 1e-16f), i3 = 1.f / (s3 + 1e-16f);
  int head = p >> 2;
  float Ih   = head == 0 ? i0 : head == 1 ? i1 : head == 2 ? i2 : i3;
  float advh = head == 0 ? adv.x : head == 1 ? adv.y : head == 2 ? adv.z : adv.w;
  lgkm0();  // stash visible within wave
  // Phase B: 2-deep pipeline; src + alpha from LDS stash (exec-mask safe)
  float acc[16] = {};
  int j = beg + g;
  bool have = j < end;
  float x_c = 0.f; uint4 v0_c = {}, v1_c = {};
  if (have) {
    int slot = j - beg;
    int sn;
    if (slot < 128) { sn = sls[w][slot]; x_c = els[w][slot][head]; }
    else {
      sn = srcs[j];
      float4 a = *(const float4*)(as + (size_t)sn * 4);
      float ah = head == 0 ? a.x : head == 1 ? a.y : head == 2 ? a.z : a.w;
      x_c = __expf(LRELU(ah + advh));
    }
    const unsigned short* hp = hb + (size_t)sn * 256 + p * 16;
    v0_c = *(const uint4*)(hp);
    v1_c = *(const uint4*)(hp + 8);
  }
  while (have) {
    int jn = j + 4;
    bool have_n = jn < end;
    float x_n = 0.f; uint4 v0_n = {}, v1_n = {};
    if (have_n) {
      int slot = jn - beg;
      int sn;
      if (slot < 128) { sn = sls[w][slot]; x_n = els[w][slot][head]; }
      else {
        sn = srcs[jn];
        float4 a = *(const float4*)(as + (size_t)sn * 4);
        float ah = head == 0 ? a.x : head == 1 ? a.y : head == 2 ? a.z : a.w;
        x_n = __expf(LRELU(ah + advh));
      }
      const unsigned short* hp = hb + (size_t)sn * 256 + p * 16;
      v0_n = *(const uint4*)(hp);
      v1_n = *(const uint4*)(hp + 8);
    }
    float al = x_c * Ih;
    acc[0]  = fmaf(al, bflo(v0_c.x), acc[0]);  acc[1]  = fmaf(al, bfhi(v0_c.x), acc[1]);
    acc[2]  = fmaf(al, bflo(v0_c.y), acc[2]);  acc[3]  = fmaf(al, bfhi(v0_c.y), acc[3]);
    acc[4]  = fmaf(al, bflo(v0_c.z), acc[4]);  acc[5]  = fmaf(al, bfhi(v0_c.z), acc[5]);
    acc[6]  = fmaf(al, bflo(v0_c.w), acc[6]);  acc[7]  = fmaf(al, bfhi(v0_c.w), acc[7]);
    acc[8]  = fmaf(al, bflo(v1_c.x), acc[8]);  acc[9]  = fmaf(al, bfhi(v1_c.x), acc[9]);
    acc[10] = fmaf(al, bflo(v1_c.y), acc[10]); acc[11] = fmaf(al, bfhi(v1_c.y), acc[11]);
    acc[12] = fmaf(al, bflo(v1_c.z), acc[12]); acc[13] = fmaf(al, bfhi(v1_c.z), acc[13]);
    acc[14] = fmaf(al, bflo(v1_c.w), acc[14]); acc[15] = fmaf(al, bfhi(v1_c.w), acc[15]);
    j = jn; have = have_n; x_c = x_n; v0_c = v0_n; v1_c = v1_n;
  }
#pragma unroll
  for (int i = 0; i < 16; ++i) acc[i] += __shfl_xor(acc[i], 16);
#pragma unroll
  for (int i = 0; i < 16; ++i) acc[i] += __shfl_xor(acc[i], 32);
  float o0 = g == 0 ? acc[0] : g == 1 ? acc[4]  : g == 2 ? acc[8]  : acc[12];
  float o1 = g == 0 ? acc[1] : g == 1 ? acc[5]  : g == 2 ? acc[9]  : acc[13];
  float o2 = g == 0 ? acc[2] : g == 1 ? acc[6]  : g == 2 ? acc[10] : acc[14];
  float o3 = g == 0 ? acc[3] : g == 1 ? acc[7]  : g == 2 ? acc[11] : acc[15];
  int c = p * 16 + g * 4;
  ushort4 ov;
  ov.x = f2bf(fmaxf(o0 + bias[c + 0], 0.f));
  ov.y = f2bf(fmaxf(o1 + bias[c + 1], 0.f));
  ov.z = f2bf(fmaxf(o2 + bias[c + 2], 0.f));
  ov.w = f2bf(fmaxf(o3 + bias[c + 3], 0.f));
  *(ushort4*)(oh + (size_t)gw * 256 + c) = ov;
}

// ---- layer-2 aggregation: no-max softmax, exp+src stash; g in [0,8), 8 ch p ----
__global__ __launch_bounds__(256) void agg1(const unsigned short* __restrict__ hb,
                                            const float* __restrict__ as,
                                            const float* __restrict__ ad,
                                            const int* __restrict__ row_ptr,
                                            const int* __restrict__ srcs,
                                            const float* __restrict__ bias,
                                            float* __restrict__ out, int N) {
  __shared__ float els[4][128];
  __shared__ int   sls[4][128];
  int tid = threadIdx.x;
  int w = tid >> 6, l = tid & 63;
  int gw = (blockIdx.x << 2) + w;
  if (gw >= N) gw = N - 1;
  int g = l >> 3, p = l & 7;
  int beg = row_ptr[gw], end = row_ptr[gw + 1];
  float adn = ad[gw];
  float s = 0.f;
  for (int j = beg + l; j < end; j += 64) {
    int sn = srcs[j];
    float x = __expf(LRELU(as[sn] + adn));
    int slot = j - beg;
    if (slot < 128) { els[w][slot] = x; sls[w][slot] = sn; }
    s += x;
  }
#pragma unroll
  for (int o = 32; o; o >>= 1) s += __shfl_xor(s, o);
  float inv = 1.f / (s + 1e-16f);
  lgkm0();
  float acc[8] = {};
  int j = beg + g;
  bool have = j < end;
  float x_c = 0.f; uint4 v_c = {};
  if (have) {
    int slot = j - beg;
    int sn;
    if (slot < 128) { sn = sls[w][slot]; x_c = els[w][slot]; }
    else { sn = srcs[j]; x_c = __expf(LRELU(as[sn] + adn)); }
    v_c = *(const uint4*)(hb + (size_t)sn * 64 + p * 8);
  }
  while (have) {
    int jn = j + 8;
    bool have_n = jn < end;
    float x_n = 0.f; uint4 v_n = {};
    if (have_n) {
      int slot = jn - beg;
      int sn;
      if (slot < 128) { sn = sls[w][slot]; x_n = els[w][slot]; }
      else { sn = srcs[jn]; x_n = __expf(LRELU(as[sn] + adn)); }
      v_n = *(const uint4*)(hb + (size_t)sn * 64 + p * 8);
    }
    float al = x_c * inv;
    acc[0] = fmaf(al, bflo(v_c.x), acc[0]); acc[1] = fmaf(al, bfhi(v_c.x), acc[1]);
    acc[2] = fmaf(al, bflo(v_c.y), acc[2]); acc[3] = fmaf(al, bfhi(v_c.y), acc[3]);
    acc[4] = fmaf(al, bflo(v_c.z), acc[4]); acc[5] = fmaf(al, bfhi(v_c.z), acc[5]);
    acc[6] = fmaf(al, bflo(v_c.w), acc[6]); acc[7] = fmaf(al, bfhi(v_c.w), acc[7]);
    j = jn; have = have_n; x_c = x_n; v_c = v_n;
  }
#pragma unroll
  for (int i = 0; i < 8; ++i) acc[i] += __shfl_xor(acc[i], 8);
#pragma unroll
  for (int i = 0; i < 8; ++i) acc[i] += __shfl_xor(acc[i], 16);
#pragma unroll
  for (int i = 0; i < 8; ++i) acc[i] += __shfl_xor(acc[i], 32);
  float ov = g == 0 ? acc[0] : g == 1 ? acc[1] : g == 2 ? acc[2] : g == 3 ? acc[3]
           : g == 4 ? acc[4] : g == 5 ? acc[5] : g == 6 ? acc[6] : acc[7];
  int c = p * 8 + g;
  out[(size_t)gw * 64 + c] = ov + bias[c];
}

extern "C" void kernel_launch(void* const* d_in, const int* in_sizes, int n_in,
                              void* d_out, int out_size, void* d_ws, size_t ws_size,
                              hipStream_t stream) {
  const float* x      = (const float*)d_in[0];
  const void*  ei     = d_in[1];
  const float* W1     = (const float*)d_in[2];
  const float* a_src1 = (const float*)d_in[3];
  const float* a_dst1 = (const float*)d_in[4];
  const float* b1     = (const float*)d_in[5];
  const float* W2     = (const float*)d_in[6];
  const float* a_src2 = (const float*)d_in[7];
  const float* a_dst2 = (const float*)d_in[8];
  const float* b2     = (const float*)d_in[9];

  const int Fin = 128;
  const int N   = in_sizes[0] / Fin;  // 50000
  const int E   = in_sizes[1] / 2;    // 800000
  const int HC1 = in_sizes[2] / Fin;  // 256
  const int Etot = E + N;

  char* wp = (char*)d_ws;
  auto alloc = [&](size_t bytes) {
    void* p = (void*)wp;
    wp += (bytes + 255) & ~(size_t)255;
    return p;
  };
  int* counts    = (int*)alloc((size_t)N * 4);
  int* row_ptr   = (int*)alloc((size_t)(N + 1) * 4);
  int* cursor    = (int*)alloc((size_t)N * 4);
  int* partial   = (int*)alloc((size_t)N * 4);
  int* blocksums = (int*)alloc(4096);
  int* srcs      = (int*)alloc((size_t)Etot * 4);
  unsigned short* xh   = (unsigned short*)alloc((size_t)N * Fin * 2);   // 12.8MB
  unsigned short* xpad = (unsigned short*)alloc((size_t)N * Fin * 2);   // o1h tail region
  unsigned short* W1th = (unsigned short*)alloc((size_t)HC1 * Fin * 2);
  unsigned short* W1tl = (unsigned short*)alloc((size_t)HC1 * Fin * 2);
  unsigned short* W2th = (unsigned short*)alloc((size_t)64 * HC1 * 2);
  unsigned short* W2tl = (unsigned short*)alloc((size_t)64 * HC1 * 2);
  unsigned short* h1b  = (unsigned short*)alloc((size_t)N * 256 * 2);   // 25.6MB
  float* as1 = (float*)alloc((size_t)N * 4 * 4);
  float* ad1 = (float*)alloc((size_t)N * 4 * 4);
  float* as2 = (float*)alloc((size_t)N * 4);
  float* ad2 = (float*)alloc((size_t)N * 4);
  (void)xpad;
  unsigned short* o1h = xh;   // xh dead after gemm1; xh+xpad = 25.6MB contiguous
  unsigned short* h2b = h1b;  // h1b dead after agg4

  const int SB = (N + 511) / 512;
  const int n4 = N * Fin / 4;
  const int nbX  = (n4 + 255) / 256;
  const int nbW1 = (Fin * HC1 + 255) / 256;
  const int nbW2 = (HC1 * 64 + 255) / 256;
  const int nbH  = (Etot + 255) / 256;

  // ---- fused prep (tobf16 | wprep1 | wprep2 | hist) ----
  hipMemsetAsync(counts, 0, (size_t)N * 4, stream);
  prep_all<<<nbX + nbW1 + nbW2 + nbH, 256, 0, stream>>>(
      x, xh, n4, W1, W1th, W1tl, W2, W2th, W2tl, ei, counts, E, N, nbX, nbW1, nbW2);

  // ---- CSR scan + scatter ----
  scan1_kernel<<<SB, 512, 0, stream>>>(counts, partial, blocksums, N);
  scan23_kernel<<<(N + 255) / 256, 256, 0, stream>>>(partial, blocksums, row_ptr, cursor, N, SB);
  scatter_kernel<<<(Etot + 255) / 256, 256, 0, stream>>>(ei, cursor, srcs, E, N);

  // ---- layer 1: fused-seg MFMA GEMM (xh@Wh + xh@Wl), 128x128 tiles, 2x2 waves ----
  gemm_mfma<128, 128, 2, 2, 4><<<dim3(2, (N + 127) / 128), 256, 0, stream>>>(
      xh, W1th, W1tl, N, Fin, h1b, 256, a_src1, a_dst1, as1, ad1);
  agg4<<<(N + 3) / 4, 256, 0, stream>>>(h1b, as1, ad1, row_ptr, srcs, b1, o1h, N);

  // ---- layer 2: fused-seg MFMA GEMM (o1h@W2h + o1h@W2l), 64x64 tiles, 4x1 waves ----
  gemm_mfma<64, 64, 4, 1, 1><<<dim3(1, (N + 63) / 64), 256, 0, stream>>>(
      o1h, W2th, W2tl, N, HC1, h2b, 64, a_src2, a_dst2, as2, ad2);
  agg1<<<(N + 3) / 4, 256, 0, stream>>>(h2b, as2, ad2, row_ptr, srcs, b2, (float*)d_out, N);
}

// Round 16
// 211.558 us; speedup vs baseline: 1.8799x; 1.1328x over previous
//
#include <hip/hip_runtime.h>

#define LRELU(x) ((x) > 0.f ? (x) : 0.2f * (x))

typedef __attribute__((ext_vector_type(8))) short bf16x8;
typedef __attribute__((ext_vector_type(4))) float f32x4;

__device__ __forceinline__ unsigned short f2bf(float f) {
  unsigned int u = __float_as_uint(f);
  unsigned int r = (u + 0x7fffu + ((u >> 16) & 1u)) >> 16;  // RNE
  return (unsigned short)r;
}
__device__ __forceinline__ float bf2f(unsigned short u) {
  return __uint_as_float(((unsigned int)u) << 16);
}
__device__ __forceinline__ float bflo(unsigned int u) { return __uint_as_float(u << 16); }
__device__ __forceinline__ float bfhi(unsigned int u) { return __uint_as_float(u & 0xffff0000u); }

__device__ __forceinline__ void lgkm0() { asm volatile("s_waitcnt lgkmcnt(0)" ::: "memory"); }

template <int NL>
__device__ __forceinline__ void wait_vmN() {
  if constexpr (NL == 2)      asm volatile("s_waitcnt vmcnt(2)" ::: "memory");
  else if constexpr (NL == 3) asm volatile("s_waitcnt vmcnt(3)" ::: "memory");
  else if constexpr (NL == 4) asm volatile("s_waitcnt vmcnt(4)" ::: "memory");
  else if constexpr (NL == 5) asm volatile("s_waitcnt vmcnt(5)" ::: "memory");
  else if constexpr (NL == 6) asm volatile("s_waitcnt vmcnt(6)" ::: "memory");
  else                        asm volatile("s_waitcnt vmcnt(0)" ::: "memory");
}
__device__ __forceinline__ void wait_vm0() { asm volatile("s_waitcnt vmcnt(0)" ::: "memory"); }

#define GLOAD_LDS16(g, l)                                                  \
  __builtin_amdgcn_global_load_lds(                                        \
      (const __attribute__((address_space(1))) void*)(g),                  \
      (__attribute__((address_space(3))) void*)(l), 16, 0, 0)

// ---- per-wave edge dtype detection ----
__device__ __forceinline__ int wave_detect64(const void* ei) {
  const int* w = (const int*)ei;
  int l = threadIdx.x & 63;
  int v = w[2 * l + 1] | w[2 * l + 129];
  return __ballot(v != 0) == 0ull;  // 1 => int64 layout
}
__device__ __forceinline__ int edge_at(const void* ei, long long idx, int is64) {
  if (is64) return (int)((const long long*)ei)[idx];
  return ((const int*)ei)[idx];
}

// ---- fused prep: tobf16(x) | wprep(W1) | wprep(W2) | hist(+rank), 4-edge ILP ----
__global__ __launch_bounds__(256) void prep_all(
    const float* __restrict__ x, unsigned short* __restrict__ xh, int n4,
    const float* __restrict__ W1, unsigned short* __restrict__ W1th,
    unsigned short* __restrict__ W1tl,
    const float* __restrict__ W2, unsigned short* __restrict__ W2th,
    unsigned short* __restrict__ W2tl,
    const void* __restrict__ ei, int* __restrict__ counts, int* __restrict__ rank,
    int E, int N, int nbX, int nbW1, int nbW2, int nbH4) {
  int b = blockIdx.x;
  int tid = threadIdx.x;
  if (b < nbX) {
    int i = b * 256 + tid;
    if (i < n4) {
      float4 v = ((const float4*)x)[i];
      ushort4 h;
      h.x = f2bf(v.x); h.y = f2bf(v.y); h.z = f2bf(v.z); h.w = f2bf(v.w);
      ((ushort4*)xh)[i] = h;
    }
    return;
  }
  b -= nbX;
  if (b < nbW1) {
    int idx = b * 256 + tid;
    const int K = 128, Nc = 256;
    if (idx < K * Nc) {
      int n = idx / K, k = idx - n * K;
      float v = W1[(size_t)k * Nc + n];
      unsigned short h = f2bf(v);
      W1th[idx] = h;
      W1tl[idx] = f2bf(v - bf2f(h));
    }
    return;
  }
  b -= nbW1;
  if (b < nbW2) {
    int idx = b * 256 + tid;
    const int K = 256, Nc = 64;
    if (idx < K * Nc) {
      int n = idx / K, k = idx - n * K;
      float v = W2[(size_t)k * Nc + n];
      unsigned short h = f2bf(v);
      W2th[idx] = h;
      W2tl[idx] = f2bf(v - bf2f(h));
    }
    return;
  }
  b -= nbW2;
  // hist + rank capture; 4 edges per thread (independent atomics in flight)
  int is64 = wave_detect64(ei);
  int tot = E + N;
  int stride = nbH4 * 256;
  int base = b * 256 + tid;
#pragma unroll
  for (int k = 0; k < 4; ++k) {
    int i = base + k * stride;
    if (i < tot) {
      int d = (i < E) ? edge_at(ei, (long long)E + i, is64) : (i - E);
      int r = atomicAdd(&counts[d], 1);
      rank[i] = r;
    }
  }
}

// ---- CSR scan (pass 1: per-512-block inclusive) ----
__global__ __launch_bounds__(512) void scan1_kernel(const int* __restrict__ counts,
                                                    int* __restrict__ partial,
                                                    int* __restrict__ blocksums, int N) {
  __shared__ int sm[1024];
  int t = threadIdx.x;
  int i = blockIdx.x * 512 + t;
  int v = (i < N) ? counts[i] : 0;
  int* cur = sm; int* nxt = sm + 512;
  cur[t] = v;
  __syncthreads();
  for (int off = 1; off < 512; off <<= 1) {
    int x = cur[t];
    if (t >= off) x += cur[t - off];
    nxt[t] = x;
    __syncthreads();
    int* tmp = cur; cur = nxt; nxt = tmp;
  }
  if (i < N) partial[i] = cur[t];
  if (t == 511) blocksums[blockIdx.x] = cur[511];
}

// ---- fused scan2+scan3: redundant wave-scan of blocksums, then elementwise ----
__global__ __launch_bounds__(256) void scan23_kernel(const int* __restrict__ partial,
                                                     const int* __restrict__ bs,
                                                     int* __restrict__ row_ptr, int N, int SB) {
  __shared__ int bsp[128];
  int tid = threadIdx.x;
  if (tid < 64) {
    int l = tid;
    int a0 = (l < SB) ? bs[l] : 0;
    int a1 = (l + 64 < SB) ? bs[l + 64] : 0;
    int s0 = a0, s1 = a1;
#pragma unroll
    for (int o = 1; o < 64; o <<= 1) {
      int t0 = __shfl_up(s0, o);
      int t1 = __shfl_up(s1, o);
      if (l >= o) { s0 += t0; s1 += t1; }
    }
    int tot0 = __shfl(s0, 63);
    bsp[l] = s0 - a0;          // exclusive prefix
    bsp[l + 64] = tot0 + s1 - a1;
  }
  __syncthreads();
  int i = blockIdx.x * 256 + tid;
  if (i == 0) row_ptr[0] = 0;
  if (i < N) row_ptr[i + 1] = partial[i] + bsp[i >> 9];
}

// ---- scatter: atomic-free via precomputed rank; 4 edges per thread ----
__global__ void scatter_kernel(const void* __restrict__ ei,
                               const int* __restrict__ row_ptr,
                               const int* __restrict__ rank,
                               int* __restrict__ srcs, int E, int N) {
  int is64 = wave_detect64(ei);
  int tot = E + N;
  int stride = gridDim.x * 256;
  int base = blockIdx.x * 256 + threadIdx.x;
#pragma unroll
  for (int k = 0; k < 4; ++k) {
    int i = base + k * stride;
    if (i < tot) {
      int s, d;
      if (i < E) {
        s = edge_at(ei, i, is64);
        d = edge_at(ei, (long long)E + i, is64);
      } else {
        s = i - E; d = s;
      }
      srcs[row_ptr[d] + rank[i]] = s;
    }
  }
}

// ---- MFMA GEMM, fused segments: per k-step stage {A, B0, B1}, acc += A@B0 + A@B1 ----
template <int BROWS, int BCOLS, int WM, int WN, int H>
__global__ __launch_bounds__(256) void gemm_mfma(
    const unsigned short* __restrict__ A0, const unsigned short* __restrict__ B0,
    const unsigned short* __restrict__ B1, int M, int Ka,
    unsigned short* __restrict__ Cb, int ldc, const float* __restrict__ asrc,
    const float* __restrict__ adst, float* __restrict__ as, float* __restrict__ ad) {
  constexpr int WROWS = BROWS / WM;
  constexpr int WCOLS = BCOLS / WN;
  constexpr int MR = WROWS / 16;
  constexpr int NR = WCOLS / 16;
  constexpr int CH_A = BROWS / 64;
  constexpr int CH_B = BCOLS / 64;
  constexpr int NLOADS = CH_A + 2 * CH_B;
  __shared__ __align__(16) unsigned short Asm[2][4][BROWS][8];
  __shared__ __align__(16) unsigned short Bsm[2][2][4][BCOLS][8];
  int tid = threadIdx.x;
  int w = tid >> 6, l = tid & 63;
  int wm = w / WN, wn = w % WN;
  int l16 = l & 15, lg = l >> 4;
  int rowbase = blockIdx.y * BROWS;
  int colbase = blockIdx.x * BCOLS;
  int wrow = wm * WROWS, wcol = wn * WCOLS;
  const int KS = Ka / 32;

  auto stage = [&](int buf, int s) {
    int kk = s * 32;
#pragma unroll
    for (int q = 0; q < CH_A; ++q) {
      int i = q * 256 + tid;
      int p = i / BROWS, r = i % BROWS;
      int gr = rowbase + r;
      if (gr >= M) gr = M - 1;
      const unsigned short* src = A0 + (size_t)gr * Ka + kk + p * 8;
      unsigned short* dst = &Asm[buf][0][0][0] + ((size_t)q * 256 + (tid & ~63)) * 8;
      GLOAD_LDS16(src, dst);
    }
#pragma unroll
    for (int seg = 0; seg < 2; ++seg) {
      const unsigned short* Bp = seg ? B1 : B0;
#pragma unroll
      for (int q = 0; q < CH_B; ++q) {
        int i = q * 256 + tid;
        int p = i / BCOLS, r = i % BCOLS;
        const unsigned short* src = Bp + (size_t)(colbase + r) * Ka + kk + p * 8;
        unsigned short* dst = &Bsm[buf][seg][0][0][0] + ((size_t)q * 256 + (tid & ~63)) * 8;
        GLOAD_LDS16(src, dst);
      }
    }
  };

  f32x4 acc[MR][NR] = {};
  stage(0, 0);
  int buf = 0;
  for (int s = 0; s < KS; ++s) {
    if (s + 1 < KS) { stage(buf ^ 1, s + 1); wait_vmN<NLOADS>(); }
    else            { wait_vm0(); }
    __builtin_amdgcn_s_barrier();
    bf16x8 af[MR], bf0[NR], bf1[NR];
#pragma unroll
    for (int m = 0; m < MR; ++m) af[m] = *(const bf16x8*)&Asm[buf][lg][wrow + m * 16 + l16][0];
#pragma unroll
    for (int n = 0; n < NR; ++n) {
      bf0[n] = *(const bf16x8*)&Bsm[buf][0][lg][wcol + n * 16 + l16][0];
      bf1[n] = *(const bf16x8*)&Bsm[buf][1][lg][wcol + n * 16 + l16][0];
    }
#pragma unroll
    for (int m = 0; m < MR; ++m)
#pragma unroll
      for (int n = 0; n < NR; ++n)
        acc[m][n] = __builtin_amdgcn_mfma_f32_16x16x32_bf16(af[m], bf0[n], acc[m][n], 0, 0, 0);
#pragma unroll
    for (int m = 0; m < MR; ++m)
#pragma unroll
      for (int n = 0; n < NR; ++n)
        acc[m][n] = __builtin_amdgcn_mfma_f32_16x16x32_bf16(af[m], bf1[n], acc[m][n], 0, 0, 0);
    __builtin_amdgcn_s_barrier();
    buf ^= 1;
  }
#pragma unroll
  for (int m = 0; m < MR; ++m) {
    int r = rowbase + wrow + m * 16 + lg * 4;
#pragma unroll
    for (int n = 0; n < NR; ++n) {
      int c = colbase + wcol + n * 16 + l16;
#pragma unroll
      for (int j = 0; j < 4; ++j) {
        if (r + j < M) Cb[(size_t)(r + j) * ldc + c] = f2bf(acc[m][n][j]);
      }
    }
  }
  float asv[NR], adv_[NR];
#pragma unroll
  for (int n = 0; n < NR; ++n) {
    int c = colbase + wcol + n * 16 + l16;
    asv[n] = asrc[c];
    adv_[n] = adst[c];
  }
  int head = (H == 1) ? 0 : ((colbase + wcol) >> 6);
#pragma unroll
  for (int m = 0; m < MR; ++m) {
#pragma unroll
    for (int j = 0; j < 4; ++j) {
      float ps = 0.f, pd = 0.f;
#pragma unroll
      for (int n = 0; n < NR; ++n) {
        ps = fmaf(acc[m][n][j], asv[n], ps);
        pd = fmaf(acc[m][n][j], adv_[n], pd);
      }
#pragma unroll
      for (int o = 1; o < 16; o <<= 1) { ps += __shfl_xor(ps, o); pd += __shfl_xor(pd, o); }
      int r = rowbase + wrow + m * 16 + lg * 4 + j;
      if (l16 == 0 && r < M) {
        as[(size_t)r * H + head] = ps;
        ad[(size_t)r * H + head] = pd;
      }
    }
  }
}

// ---- layer-1 aggregation: no-max softmax, exp+src stashed in LDS, 2-deep pipe ----
__global__ __launch_bounds__(256) void agg4(const unsigned short* __restrict__ hb,
                                            const float* __restrict__ as,
                                            const float* __restrict__ ad,
                                            const int* __restrict__ row_ptr,
                                            const int* __restrict__ srcs,
                                            const float* __restrict__ bias,
                                            unsigned short* __restrict__ oh, int N) {
  __shared__ float els[4][128][4];  // exp(e) per slot per head
  __shared__ int   sls[4][128];     // src index per slot
  int tid = threadIdx.x;
  int w = tid >> 6, l = tid & 63;
  int gw = (blockIdx.x << 2) + w;
  if (gw >= N) gw = N - 1;
  int g = l >> 4, p = l & 15;
  int beg = row_ptr[gw], end = row_ptr[gw + 1];
  float4 adv = *(const float4*)(ad + (size_t)gw * 4);
  // Phase A: one strided pass: exp(e) -> stash + sum; src index -> stash
  float s0 = 0.f, s1 = 0.f, s2 = 0.f, s3 = 0.f;
  for (int j = beg + l; j < end; j += 64) {
    int sn = srcs[j];
    float4 a = *(const float4*)(as + (size_t)sn * 4);
    float x0 = __expf(LRELU(a.x + adv.x));
    float x1 = __expf(LRELU(a.y + adv.y));
    float x2 = __expf(LRELU(a.z + adv.z));
    float x3 = __expf(LRELU(a.w + adv.w));
    int slot = j - beg;
    if (slot < 128) {
      els[w][slot][0] = x0; els[w][slot][1] = x1;
      els[w][slot][2] = x2; els[w][slot][3] = x3;
      sls[w][slot] = sn;
    }
    s0 += x0; s1 += x1; s2 += x2; s3 += x3;
  }
#pragma unroll
  for (int o = 32; o; o >>= 1) {
    s0 += __shfl_xor(s0, o); s1 += __shfl_xor(s1, o);
    s2 += __shfl_xor(s2, o); s3 += __shfl_xor(s3, o);
  }
  float i0 = 1.f / (s0 + 1e-16f), i1 = 1.f / (s1 + 1e-16f);
  float i2 = 1.f / (s2 + 1e-16f), i3 = 1.f / (s3 + 1e-16f);
  int head = p >> 2;
  float Ih   = head == 0 ? i0 : head == 1 ? i1 : head == 2 ? i2 : i3;
  float advh = head == 0 ? adv.x : head == 1 ? adv.y : head == 2 ? adv.z : adv.w;
  lgkm0();  // stash visible within wave
  // Phase B: 2-deep pipeline; src + alpha from LDS stash (exec-mask safe)
  float acc[16] = {};
  int j = beg + g;
  bool have = j < end;
  float x_c = 0.f; uint4 v0_c = {}, v1_c = {};
  if (have) {
    int slot = j - beg;
    int sn;
    if (slot < 128) { sn = sls[w][slot]; x_c = els[w][slot][head]; }
    else {
      sn = srcs[j];
      float4 a = *(const float4*)(as + (size_t)sn * 4);
      float ah = head == 0 ? a.x : head == 1 ? a.y : head == 2 ? a.z : a.w;
      x_c = __expf(LRELU(ah + advh));
    }
    const unsigned short* hp = hb + (size_t)sn * 256 + p * 16;
    v0_c = *(const uint4*)(hp);
    v1_c = *(const uint4*)(hp + 8);
  }
  while (have) {
    int jn = j + 4;
    bool have_n = jn < end;
    float x_n = 0.f; uint4 v0_n = {}, v1_n = {};
    if (have_n) {
      int slot = jn - beg;
      int sn;
      if (slot < 128) { sn = sls[w][slot]; x_n = els[w][slot][head]; }
      else {
        sn = srcs[jn];
        float4 a = *(const float4*)(as + (size_t)sn * 4);
        float ah = head == 0 ? a.x : head == 1 ? a.y : head == 2 ? a.z : a.w;
        x_n = __expf(LRELU(ah + advh));
      }
      const unsigned short* hp = hb + (size_t)sn * 256 + p * 16;
      v0_n = *(const uint4*)(hp);
      v1_n = *(const uint4*)(hp + 8);
    }
    float al = x_c * Ih;
    acc[0]  = fmaf(al, bflo(v0_c.x), acc[0]);  acc[1]  = fmaf(al, bfhi(v0_c.x), acc[1]);
    acc[2]  = fmaf(al, bflo(v0_c.y), acc[2]);  acc[3]  = fmaf(al, bfhi(v0_c.y), acc[3]);
    acc[4]  = fmaf(al, bflo(v0_c.z), acc[4]);  acc[5]  = fmaf(al, bfhi(v0_c.z), acc[5]);
    acc[6]  = fmaf(al, bflo(v0_c.w), acc[6]);  acc[7]  = fmaf(al, bfhi(v0_c.w), acc[7]);
    acc[8]  = fmaf(al, bflo(v1_c.x), acc[8]);  acc[9]  = fmaf(al, bfhi(v1_c.x), acc[9]);
    acc[10] = fmaf(al, bflo(v1_c.y), acc[10]); acc[11] = fmaf(al, bfhi(v1_c.y), acc[11]);
    acc[12] = fmaf(al, bflo(v1_c.z), acc[12]); acc[13] = fmaf(al, bfhi(v1_c.z), acc[13]);
    acc[14] = fmaf(al, bflo(v1_c.w), acc[14]); acc[15] = fmaf(al, bfhi(v1_c.w), acc[15]);
    j = jn; have = have_n; x_c = x_n; v0_c = v0_n; v1_c = v1_n;
  }
#pragma unroll
  for (int i = 0; i < 16; ++i) acc[i] += __shfl_xor(acc[i], 16);
#pragma unroll
  for (int i = 0; i < 16; ++i) acc[i] += __shfl_xor(acc[i], 32);
  float o0 = g == 0 ? acc[0] : g == 1 ? acc[4]  : g == 2 ? acc[8]  : acc[12];
  float o1 = g == 0 ? acc[1] : g == 1 ? acc[5]  : g == 2 ? acc[9]  : acc[13];
  float o2 = g == 0 ? acc[2] : g == 1 ? acc[6]  : g == 2 ? acc[10] : acc[14];
  float o3 = g == 0 ? acc[3] : g == 1 ? acc[7]  : g == 2 ? acc[11] : acc[15];
  int c = p * 16 + g * 4;
  ushort4 ov;
  ov.x = f2bf(fmaxf(o0 + bias[c + 0], 0.f));
  ov.y = f2bf(fmaxf(o1 + bias[c + 1], 0.f));
  ov.z = f2bf(fmaxf(o2 + bias[c + 2], 0.f));
  ov.w = f2bf(fmaxf(o3 + bias[c + 3], 0.f));
  *(ushort4*)(oh + (size_t)gw * 256 + c) = ov;
}

// ---- layer-2 aggregation: no-max softmax, exp+src stash; g in [0,8), 8 ch p ----
__global__ __launch_bounds__(256) void agg1(const unsigned short* __restrict__ hb,
                                            const float* __restrict__ as,
                                            const float* __restrict__ ad,
                                            const int* __restrict__ row_ptr,
                                            const int* __restrict__ srcs,
                                            const float* __restrict__ bias,
                                            float* __restrict__ out, int N) {
  __shared__ float els[4][128];
  __shared__ int   sls[4][128];
  int tid = threadIdx.x;
  int w = tid >> 6, l = tid & 63;
  int gw = (blockIdx.x << 2) + w;
  if (gw >= N) gw = N - 1;
  int g = l >> 3, p = l & 7;
  int beg = row_ptr[gw], end = row_ptr[gw + 1];
  float adn = ad[gw];
  float s = 0.f;
  for (int j = beg + l; j < end; j += 64) {
    int sn = srcs[j];
    float x = __expf(LRELU(as[sn] + adn));
    int slot = j - beg;
    if (slot < 128) { els[w][slot] = x; sls[w][slot] = sn; }
    s += x;
  }
#pragma unroll
  for (int o = 32; o; o >>= 1) s += __shfl_xor(s, o);
  float inv = 1.f / (s + 1e-16f);
  lgkm0();
  float acc[8] = {};
  int j = beg + g;
  bool have = j < end;
  float x_c = 0.f; uint4 v_c = {};
  if (have) {
    int slot = j - beg;
    int sn;
    if (slot < 128) { sn = sls[w][slot]; x_c = els[w][slot]; }
    else { sn = srcs[j]; x_c = __expf(LRELU(as[sn] + adn)); }
    v_c = *(const uint4*)(hb + (size_t)sn * 64 + p * 8);
  }
  while (have) {
    int jn = j + 8;
    bool have_n = jn < end;
    float x_n = 0.f; uint4 v_n = {};
    if (have_n) {
      int slot = jn - beg;
      int sn;
      if (slot < 128) { sn = sls[w][slot]; x_n = els[w][slot]; }
      else { sn = srcs[jn]; x_n = __expf(LRELU(as[sn] + adn)); }
      v_n = *(const uint4*)(hb + (size_t)sn * 64 + p * 8);
    }
    float al = x_c * inv;
    acc[0] = fmaf(al, bflo(v_c.x), acc[0]); acc[1] = fmaf(al, bfhi(v_c.x), acc[1]);
    acc[2] = fmaf(al, bflo(v_c.y), acc[2]); acc[3] = fmaf(al, bfhi(v_c.y), acc[3]);
    acc[4] = fmaf(al, bflo(v_c.z), acc[4]); acc[5] = fmaf(al, bfhi(v_c.z), acc[5]);
    acc[6] = fmaf(al, bflo(v_c.w), acc[6]); acc[7] = fmaf(al, bfhi(v_c.w), acc[7]);
    j = jn; have = have_n; x_c = x_n; v_c = v_n;
  }
#pragma unroll
  for (int i = 0; i < 8; ++i) acc[i] += __shfl_xor(acc[i], 8);
#pragma unroll
  for (int i = 0; i < 8; ++i) acc[i] += __shfl_xor(acc[i], 16);
#pragma unroll
  for (int i = 0; i < 8; ++i) acc[i] += __shfl_xor(acc[i], 32);
  float ov = g == 0 ? acc[0] : g == 1 ? acc[1] : g == 2 ? acc[2] : g == 3 ? acc[3]
           : g == 4 ? acc[4] : g == 5 ? acc[5] : g == 6 ? acc[6] : acc[7];
  int c = p * 8 + g;
  out[(size_t)gw * 64 + c] = ov + bias[c];
}

extern "C" void kernel_launch(void* const* d_in, const int* in_sizes, int n_in,
                              void* d_out, int out_size, void* d_ws, size_t ws_size,
                              hipStream_t stream) {
  const float* x      = (const float*)d_in[0];
  const void*  ei     = d_in[1];
  const float* W1     = (const float*)d_in[2];
  const float* a_src1 = (const float*)d_in[3];
  const float* a_dst1 = (const float*)d_in[4];
  const float* b1     = (const float*)d_in[5];
  const float* W2     = (const float*)d_in[6];
  const float* a_src2 = (const float*)d_in[7];
  const float* a_dst2 = (const float*)d_in[8];
  const float* b2     = (const float*)d_in[9];

  const int Fin = 128;
  const int N   = in_sizes[0] / Fin;  // 50000
  const int E   = in_sizes[1] / 2;    // 800000
  const int HC1 = in_sizes[2] / Fin;  // 256
  const int Etot = E + N;

  char* wp = (char*)d_ws;
  auto alloc = [&](size_t bytes) {
    void* p = (void*)wp;
    wp += (bytes + 255) & ~(size_t)255;
    return p;
  };
  int* counts    = (int*)alloc((size_t)N * 4);
  int* row_ptr   = (int*)alloc((size_t)(N + 1) * 4);
  int* partial   = (int*)alloc((size_t)N * 4);
  int* blocksums = (int*)alloc(4096);
  int* rank      = (int*)alloc((size_t)Etot * 4);
  int* srcs      = (int*)alloc((size_t)Etot * 4);
  unsigned short* xh   = (unsigned short*)alloc((size_t)N * Fin * 2);   // 12.8MB
  unsigned short* xpad = (unsigned short*)alloc((size_t)N * Fin * 2);   // o1h tail region
  unsigned short* W1th = (unsigned short*)alloc((size_t)HC1 * Fin * 2);
  unsigned short* W1tl = (unsigned short*)alloc((size_t)HC1 * Fin * 2);
  unsigned short* W2th = (unsigned short*)alloc((size_t)64 * HC1 * 2);
  unsigned short* W2tl = (unsigned short*)alloc((size_t)64 * HC1 * 2);
  unsigned short* h1b  = (unsigned short*)alloc((size_t)N * 256 * 2);   // 25.6MB
  float* as1 = (float*)alloc((size_t)N * 4 * 4);
  float* ad1 = (float*)alloc((size_t)N * 4 * 4);
  float* as2 = (float*)alloc((size_t)N * 4);
  float* ad2 = (float*)alloc((size_t)N * 4);
  (void)xpad;
  unsigned short* o1h = xh;   // xh dead after gemm1; xh+xpad = 25.6MB contiguous
  unsigned short* h2b = h1b;  // h1b dead after agg4

  const int SB = (N + 511) / 512;
  const int n4 = N * Fin / 4;
  const int nbX  = (n4 + 255) / 256;
  const int nbW1 = (Fin * HC1 + 255) / 256;
  const int nbW2 = (HC1 * 64 + 255) / 256;
  const int nbH4 = (Etot + 1023) / 1024;

  // ---- fused prep (tobf16 | wprep1 | wprep2 | hist+rank) ----
  hipMemsetAsync(counts, 0, (size_t)N * 4, stream);
  prep_all<<<nbX + nbW1 + nbW2 + nbH4, 256, 0, stream>>>(
      x, xh, n4, W1, W1th, W1tl, W2, W2th, W2tl, ei, counts, rank, E, N,
      nbX, nbW1, nbW2, nbH4);

  // ---- CSR scan + atomic-free scatter ----
  scan1_kernel<<<SB, 512, 0, stream>>>(counts, partial, blocksums, N);
  scan23_kernel<<<(N + 255) / 256, 256, 0, stream>>>(partial, blocksums, row_ptr, N, SB);
  scatter_kernel<<<nbH4, 256, 0, stream>>>(ei, row_ptr, rank, srcs, E, N);

  // ---- layer 1: fused-seg MFMA GEMM (xh@Wh + xh@Wl), 128x128 tiles, 2x2 waves ----
  gemm_mfma<128, 128, 2, 2, 4><<<dim3(2, (N + 127) / 128), 256, 0, stream>>>(
      xh, W1th, W1tl, N, Fin, h1b, 256, a_src1, a_dst1, as1, ad1);
  agg4<<<(N + 3) / 4, 256, 0, stream>>>(h1b, as1, ad1, row_ptr, srcs, b1, o1h, N);

  // ---- layer 2: fused-seg MFMA GEMM (o1h@W2h + o1h@W2l), 64x64 tiles, 4x1 waves ----
  gemm_mfma<64, 64, 4, 1, 1><<<dim3(1, (N + 63) / 64), 256, 0, stream>>>(
      o1h, W2th, W2tl, N, HC1, h2b, 64, a_src2, a_dst2, as2, ad2);
  agg1<<<(N + 3) / 4, 256, 0, stream>>>(h2b, as2, ad2, row_ptr, srcs, b2, (float*)d_out, N);
}